// Round 1
// baseline (8771.452 us; speedup 1.0000x reference)
//
#include <hip/hip_runtime.h>

#define D 128

__device__ __forceinline__ float atomAdd(float* p, float v) {
    return unsafeAtomicAdd(p, v);   // native global_atomic_add_f32 on gfx950
}

__global__ __launch_bounds__(256) void count_kernel(const int* __restrict__ dst,
                                                    float* __restrict__ cnt, int E) {
    int e = blockIdx.x * 256 + threadIdx.x;
    if (e < E) atomAdd(&cnt[dst[e]], 1.0f);
}

__global__ __launch_bounds__(256) void invcnt_kernel(float* __restrict__ cnt, int N) {
    int i = blockIdx.x * 256 + threadIdx.x;
    if (i < N) cnt[i] = 1.0f / fmaxf(cnt[i], 1.0f);
}

// 32 lanes per edge, float4 per lane: gather x[src] row, atomic-add into agg[dst] row.
__global__ __launch_bounds__(256) void scatter_kernel(const float* __restrict__ xin,
        const int* __restrict__ src, const int* __restrict__ dst,
        float* __restrict__ agg, int E) {
    int t = blockIdx.x * 256 + threadIdx.x;
    int e = t >> 5;
    if (e >= E) return;
    int lane = t & 31;
    int s = src[e], d = dst[e];
    float4 v = *reinterpret_cast<const float4*>(xin + (size_t)s * D + lane * 4);
    float* o = agg + (size_t)d * D + lane * 4;
    atomAdd(o + 0, v.x);
    atomAdd(o + 1, v.y);
    atomAdd(o + 2, v.z);
    atomAdd(o + 3, v.w);
}

// out[row][c0+col] = relu( invc[row]*sum_k Agg[row][k]*Wl[col][k]
//                          + sum_k X[row][k]*Wr[col][k] + b[col] )
// Block: 256 threads, 64-row chunk x 64-col half. Weights transposed in LDS.
// Thread tile 4x4 (rows strided by 16 to spread LDS banks), float4 LDS reads.
template<int DOUT, bool RELU>
__global__ __launch_bounds__(256) void sage_gemm(
    const float* __restrict__ Agg, const float* __restrict__ X,
    const float* __restrict__ invc,
    const float* __restrict__ Wl, const float* __restrict__ Wr,
    const float* __restrict__ bias, float* __restrict__ out, int N)
{
    __shared__ float sWlT[128][64];   // [k][col]  32 KB
    __shared__ float sWrT[128][64];   // 32 KB
    __shared__ float sA[64][132];     // mean rows, padded   33 KB
    __shared__ float sX[64][132];     // x rows              33 KB

    const int c0 = blockIdx.y * 64;
    const int tid = threadIdx.x;

    // load weights transposed into LDS (once per block)
    for (int i = tid; i < 64 * 32; i += 256) {
        int col = i & 63;
        int k4 = (i >> 6) << 2;
        float4 wl = *reinterpret_cast<const float4*>(Wl + (size_t)(c0 + col) * D + k4);
        float4 wr = *reinterpret_cast<const float4*>(Wr + (size_t)(c0 + col) * D + k4);
        sWlT[k4 + 0][col] = wl.x; sWlT[k4 + 1][col] = wl.y;
        sWlT[k4 + 2][col] = wl.z; sWlT[k4 + 3][col] = wl.w;
        sWrT[k4 + 0][col] = wr.x; sWrT[k4 + 1][col] = wr.y;
        sWrT[k4 + 2][col] = wr.z; sWrT[k4 + 3][col] = wr.w;
    }

    const int tr = tid & 15;   // row group: rows tr + 16*r
    const int tc = tid >> 4;   // col group: cols tc*4 + c
    float bb[4];
    #pragma unroll
    for (int c = 0; c < 4; ++c) bb[c] = bias[c0 + tc * 4 + c];

    for (int m0 = blockIdx.x * 64; m0 < N; m0 += gridDim.x * 64) {
        __syncthreads();   // previous chunk's readers done (also covers weight load, iter 0)
        // stage 64 rows of mean (=Agg*invc) and X
        for (int i = tid; i < 64 * 32; i += 256) {
            int r = i >> 5;
            int k4 = (i & 31) << 2;
            int row = m0 + r;
            float4 a = make_float4(0.f, 0.f, 0.f, 0.f);
            float4 xx = a;
            float ic = 0.f;
            if (row < N) {
                ic = invc[row];
                a = *reinterpret_cast<const float4*>(Agg + (size_t)row * D + k4);
                xx = *reinterpret_cast<const float4*>(X + (size_t)row * D + k4);
            }
            *reinterpret_cast<float4*>(&sA[r][k4]) =
                make_float4(a.x * ic, a.y * ic, a.z * ic, a.w * ic);
            *reinterpret_cast<float4*>(&sX[r][k4]) = xx;
        }
        __syncthreads();

        float acc[4][4] = {};
        #pragma unroll 2
        for (int k = 0; k < 128; k += 4) {
            float4 av[4], xv[4], wlv[4], wrv[4];
            #pragma unroll
            for (int r = 0; r < 4; ++r) {
                av[r] = *reinterpret_cast<const float4*>(&sA[tr + 16 * r][k]);
                xv[r] = *reinterpret_cast<const float4*>(&sX[tr + 16 * r][k]);
            }
            #pragma unroll
            for (int j = 0; j < 4; ++j) {
                wlv[j] = *reinterpret_cast<const float4*>(&sWlT[k + j][tc * 4]);
                wrv[j] = *reinterpret_cast<const float4*>(&sWrT[k + j][tc * 4]);
            }
            #pragma unroll
            for (int r = 0; r < 4; ++r) {
                const float* ap = reinterpret_cast<const float*>(&av[r]);
                const float* xp = reinterpret_cast<const float*>(&xv[r]);
                #pragma unroll
                for (int j = 0; j < 4; ++j) {
                    const float aj = ap[j], xj = xp[j];
                    const float* wlp = reinterpret_cast<const float*>(&wlv[j]);
                    const float* wrp = reinterpret_cast<const float*>(&wrv[j]);
                    #pragma unroll
                    for (int c = 0; c < 4; ++c) {
                        acc[r][c] += aj * wlp[c] + xj * wrp[c];
                    }
                }
            }
        }

        #pragma unroll
        for (int r = 0; r < 4; ++r) {
            int row = m0 + tr + 16 * r;
            if (row < N) {
                float v0 = acc[r][0] + bb[0];
                float v1 = acc[r][1] + bb[1];
                float v2 = acc[r][2] + bb[2];
                float v3 = acc[r][3] + bb[3];
                if (RELU) {
                    v0 = fmaxf(v0, 0.f); v1 = fmaxf(v1, 0.f);
                    v2 = fmaxf(v2, 0.f); v3 = fmaxf(v3, 0.f);
                }
                float4 o = make_float4(v0, v1, v2, v3);
                *reinterpret_cast<float4*>(out + (size_t)row * DOUT + c0 + tc * 4) = o;
            }
        }
    }
}

extern "C" void kernel_launch(void* const* d_in, const int* in_sizes, int n_in,
                              void* d_out, int out_size, void* d_ws, size_t ws_size,
                              hipStream_t stream) {
    const float* x   = (const float*)d_in[0];
    const float* Wl0 = (const float*)d_in[1];
    const float* Wr0 = (const float*)d_in[2];
    const float* b0  = (const float*)d_in[3];
    const float* Wl1 = (const float*)d_in[4];
    const float* Wr1 = (const float*)d_in[5];
    const float* b1  = (const float*)d_in[6];
    const float* Wl2 = (const float*)d_in[7];
    const float* Wr2 = (const float*)d_in[8];
    const float* b2  = (const float*)d_in[9];
    const int* ei    = (const int*)d_in[10];

    const int E = in_sizes[10] / 2;
    const int N = in_sizes[0] / D;
    const int* src = ei;
    const int* dst = ei + E;

    float* A   = (float*)d_ws;                  // [N][128] aggregation accumulator
    float* H0  = A  + (size_t)N * D;            // [N][128]
    float* H1  = H0 + (size_t)N * D;            // [N][128]
    float* cnt = H1 + (size_t)N * D;            // [N] degree -> inv degree

    float* out = (float*)d_out;

    // degree (same graph all layers): count once
    hipMemsetAsync(A,   0, (size_t)N * D * sizeof(float), stream);
    hipMemsetAsync(cnt, 0, (size_t)N * sizeof(float), stream);
    count_kernel<<<(E + 255) / 256, 256, 0, stream>>>(dst, cnt, E);
    invcnt_kernel<<<(N + 255) / 256, 256, 0, stream>>>(cnt, N);

    const int sgrid = (E * 32 + 255) / 256;
    dim3 g128(128, 2), g64(128, 1);

    // layer 0
    scatter_kernel<<<sgrid, 256, 0, stream>>>(x, src, dst, A, E);
    sage_gemm<128, true><<<g128, 256, 0, stream>>>(A, x, cnt, Wl0, Wr0, b0, H0, N);

    // layer 1
    hipMemsetAsync(A, 0, (size_t)N * D * sizeof(float), stream);
    scatter_kernel<<<sgrid, 256, 0, stream>>>(H0, src, dst, A, E);
    sage_gemm<128, true><<<g128, 256, 0, stream>>>(A, H0, cnt, Wl1, Wr1, b1, H1, N);

    // layer 2 (d_out = 64, no relu)
    hipMemsetAsync(A, 0, (size_t)N * D * sizeof(float), stream);
    scatter_kernel<<<sgrid, 256, 0, stream>>>(H1, src, dst, A, E);
    sage_gemm<64, false><<<g64, 256, 0, stream>>>(A, H1, cnt, Wl2, Wr2, b2, out, N);
}

// Round 2
// 1093.671 us; speedup vs baseline: 8.0202x; 8.0202x over previous
//
#include <hip/hip_runtime.h>

#define D 128

// ---------------- CSR build ----------------

__global__ __launch_bounds__(256) void hist_kernel(const int* __restrict__ dst,
                                                   int* __restrict__ cnt, int E) {
    int e = blockIdx.x * 256 + threadIdx.x;
    if (e < E) atomicAdd(&cnt[dst[e]], 1);
}

// block-level scan: 1024 elems per block (256 thr x 4), exclusive within block
__global__ __launch_bounds__(256) void scan1_kernel(const int* __restrict__ cnt,
        int* __restrict__ rowptr, int* __restrict__ blksum, int N) {
    __shared__ int sdata[256];
    const int base = blockIdx.x * 1024 + threadIdx.x * 4;
    int v0 = 0, v1 = 0, v2 = 0, v3 = 0;
    if (base + 3 < N) {
        int4 q = *reinterpret_cast<const int4*>(cnt + base);
        v0 = q.x; v1 = q.y; v2 = q.z; v3 = q.w;
    } else {
        if (base + 0 < N) v0 = cnt[base + 0];
        if (base + 1 < N) v1 = cnt[base + 1];
        if (base + 2 < N) v2 = cnt[base + 2];
    }
    const int t = v0 + v1 + v2 + v3;
    int val = t;
    sdata[threadIdx.x] = val;
    __syncthreads();
    for (int off = 1; off < 256; off <<= 1) {
        int other = (threadIdx.x >= off) ? sdata[threadIdx.x - off] : 0;
        __syncthreads();
        val += other;
        sdata[threadIdx.x] = val;
        __syncthreads();
    }
    const int excl = val - t;
    if (base + 0 < N) rowptr[base + 0] = excl;
    if (base + 1 < N) rowptr[base + 1] = excl + v0;
    if (base + 2 < N) rowptr[base + 2] = excl + v0 + v1;
    if (base + 3 < N) rowptr[base + 3] = excl + v0 + v1 + v2;
    if (threadIdx.x == 255) blksum[blockIdx.x] = val;
}

__global__ void scan2_kernel(int* __restrict__ blksum, int nb) {
    if (blockIdx.x == 0 && threadIdx.x == 0) {
        int run = 0;
        for (int i = 0; i < nb; ++i) { int v = blksum[i]; blksum[i] = run; run += v; }
        blksum[nb] = run;
    }
}

__global__ __launch_bounds__(256) void scan3_kernel(int* __restrict__ rowptr,
        const int* __restrict__ blksum, int N) {
    const int base = blockIdx.x * 1024 + threadIdx.x * 4;
    const int off = blksum[blockIdx.x];
    #pragma unroll
    for (int k = 0; k < 4; ++k)
        if (base + k < N) rowptr[base + k] += off;
    if (base == 0 && blockIdx.x == 0) rowptr[N] = blksum[gridDim.x];
}

__global__ __launch_bounds__(256) void invdeg_kernel(const int* __restrict__ rowptr,
        float* __restrict__ invd, int N) {
    int i = blockIdx.x * 256 + threadIdx.x;
    if (i < N) {
        int deg = rowptr[i + 1] - rowptr[i];
        invd[i] = 1.0f / (float)(deg > 1 ? deg : 1);
    }
}

__global__ __launch_bounds__(256) void fill_kernel(const int* __restrict__ src,
        const int* __restrict__ dst, const int* __restrict__ rowptr,
        int* __restrict__ fillc, int* __restrict__ colidx, int E) {
    int e = blockIdx.x * 256 + threadIdx.x;
    if (e < E) {
        int d = dst[e];
        int pos = rowptr[d] + atomicAdd(&fillc[d], 1);
        colidx[pos] = src[e];
    }
}

// ---------------- gather aggregation (mean) ----------------
// one wave (64 lanes) per node, float2 per lane => 512B coalesced read per edge
__global__ __launch_bounds__(256) void gather_kernel(const float* __restrict__ xin,
        const int* __restrict__ rowptr, const int* __restrict__ colidx,
        const float* __restrict__ invd, float* __restrict__ outA, int N) {
    const int node = blockIdx.x * 4 + (threadIdx.x >> 6);
    if (node >= N) return;
    const int lane = threadIdx.x & 63;
    const int beg = rowptr[node], end = rowptr[node + 1];
    float ax = 0.f, ay = 0.f;
    int j = beg;
    for (; j + 4 <= end; j += 4) {
        int s0 = colidx[j + 0], s1 = colidx[j + 1];
        int s2 = colidx[j + 2], s3 = colidx[j + 3];
        float2 v0 = *reinterpret_cast<const float2*>(xin + (size_t)s0 * D + lane * 2);
        float2 v1 = *reinterpret_cast<const float2*>(xin + (size_t)s1 * D + lane * 2);
        float2 v2 = *reinterpret_cast<const float2*>(xin + (size_t)s2 * D + lane * 2);
        float2 v3 = *reinterpret_cast<const float2*>(xin + (size_t)s3 * D + lane * 2);
        ax += v0.x + v1.x + v2.x + v3.x;
        ay += v0.y + v1.y + v2.y + v3.y;
    }
    for (; j < end; ++j) {
        int s = colidx[j];
        float2 v = *reinterpret_cast<const float2*>(xin + (size_t)s * D + lane * 2);
        ax += v.x; ay += v.y;
    }
    const float ic = invd[node];
    *reinterpret_cast<float2*>(outA + (size_t)node * D + lane * 2) =
        make_float2(ax * ic, ay * ic);
}

// ---------------- fused dual GEMM ----------------
// out[row][c0+col] = act( sum_k Mean[row][k]*Wl[col][k] + sum_k X[row][k]*Wr[col][k] + b[col] )
template<int DOUT, bool RELU>
__global__ __launch_bounds__(256) void sage_gemm(
    const float* __restrict__ Mean, const float* __restrict__ X,
    const float* __restrict__ Wl, const float* __restrict__ Wr,
    const float* __restrict__ bias, float* __restrict__ out, int N)
{
    __shared__ float sWlT[128][64];   // [k][col]  32 KB
    __shared__ float sWrT[128][64];   // 32 KB
    __shared__ float sA[64][132];     // mean rows, padded   33 KB
    __shared__ float sX[64][132];     // x rows              33 KB

    const int c0 = blockIdx.y * 64;
    const int tid = threadIdx.x;

    for (int i = tid; i < 64 * 32; i += 256) {
        int col = i & 63;
        int k4 = (i >> 6) << 2;
        float4 wl = *reinterpret_cast<const float4*>(Wl + (size_t)(c0 + col) * D + k4);
        float4 wr = *reinterpret_cast<const float4*>(Wr + (size_t)(c0 + col) * D + k4);
        sWlT[k4 + 0][col] = wl.x; sWlT[k4 + 1][col] = wl.y;
        sWlT[k4 + 2][col] = wl.z; sWlT[k4 + 3][col] = wl.w;
        sWrT[k4 + 0][col] = wr.x; sWrT[k4 + 1][col] = wr.y;
        sWrT[k4 + 2][col] = wr.z; sWrT[k4 + 3][col] = wr.w;
    }

    const int tr = tid & 15;
    const int tc = tid >> 4;
    float bb[4];
    #pragma unroll
    for (int c = 0; c < 4; ++c) bb[c] = bias[c0 + tc * 4 + c];

    for (int m0 = blockIdx.x * 64; m0 < N; m0 += gridDim.x * 64) {
        __syncthreads();
        for (int i = tid; i < 64 * 32; i += 256) {
            int r = i >> 5;
            int k4 = (i & 31) << 2;
            int row = m0 + r;
            float4 a = make_float4(0.f, 0.f, 0.f, 0.f);
            float4 xx = a;
            if (row < N) {
                a = *reinterpret_cast<const float4*>(Mean + (size_t)row * D + k4);
                xx = *reinterpret_cast<const float4*>(X + (size_t)row * D + k4);
            }
            *reinterpret_cast<float4*>(&sA[r][k4]) = a;
            *reinterpret_cast<float4*>(&sX[r][k4]) = xx;
        }
        __syncthreads();

        float acc[4][4] = {};
        #pragma unroll 2
        for (int k = 0; k < 128; k += 4) {
            float4 av[4], xv[4], wlv[4], wrv[4];
            #pragma unroll
            for (int r = 0; r < 4; ++r) {
                av[r] = *reinterpret_cast<const float4*>(&sA[tr + 16 * r][k]);
                xv[r] = *reinterpret_cast<const float4*>(&sX[tr + 16 * r][k]);
            }
            #pragma unroll
            for (int j = 0; j < 4; ++j) {
                wlv[j] = *reinterpret_cast<const float4*>(&sWlT[k + j][tc * 4]);
                wrv[j] = *reinterpret_cast<const float4*>(&sWrT[k + j][tc * 4]);
            }
            #pragma unroll
            for (int r = 0; r < 4; ++r) {
                const float* ap = reinterpret_cast<const float*>(&av[r]);
                const float* xp = reinterpret_cast<const float*>(&xv[r]);
                #pragma unroll
                for (int j = 0; j < 4; ++j) {
                    const float aj = ap[j], xj = xp[j];
                    const float* wlp = reinterpret_cast<const float*>(&wlv[j]);
                    const float* wrp = reinterpret_cast<const float*>(&wrv[j]);
                    #pragma unroll
                    for (int c = 0; c < 4; ++c) {
                        acc[r][c] += aj * wlp[c] + xj * wrp[c];
                    }
                }
            }
        }

        #pragma unroll
        for (int r = 0; r < 4; ++r) {
            int row = m0 + tr + 16 * r;
            if (row < N) {
                float v0 = acc[r][0] + bb[0];
                float v1 = acc[r][1] + bb[1];
                float v2 = acc[r][2] + bb[2];
                float v3 = acc[r][3] + bb[3];
                if (RELU) {
                    v0 = fmaxf(v0, 0.f); v1 = fmaxf(v1, 0.f);
                    v2 = fmaxf(v2, 0.f); v3 = fmaxf(v3, 0.f);
                }
                *reinterpret_cast<float4*>(out + (size_t)row * DOUT + c0 + tc * 4) =
                    make_float4(v0, v1, v2, v3);
            }
        }
    }
}

extern "C" void kernel_launch(void* const* d_in, const int* in_sizes, int n_in,
                              void* d_out, int out_size, void* d_ws, size_t ws_size,
                              hipStream_t stream) {
    const float* x   = (const float*)d_in[0];
    const float* Wl0 = (const float*)d_in[1];
    const float* Wr0 = (const float*)d_in[2];
    const float* b0  = (const float*)d_in[3];
    const float* Wl1 = (const float*)d_in[4];
    const float* Wr1 = (const float*)d_in[5];
    const float* b1  = (const float*)d_in[6];
    const float* Wl2 = (const float*)d_in[7];
    const float* Wr2 = (const float*)d_in[8];
    const float* b2  = (const float*)d_in[9];
    const int* ei    = (const int*)d_in[10];

    const int E = in_sizes[10] / 2;
    const int N = in_sizes[0] / D;
    const int* src = ei;
    const int* dst = ei + E;

    // workspace layout
    float* A      = (float*)d_ws;               // [N][128] mean buffer
    float* H0     = A  + (size_t)N * D;         // [N][128]
    float* H1     = H0 + (size_t)N * D;         // [N][128]
    float* invd   = H1 + (size_t)N * D;         // [N]
    int*   cnt    = (int*)(invd + N);           // [N] histogram, reused as fill counters
    int*   rowptr = cnt + N;                    // [N+8]
    int*   blksum = rowptr + N + 8;             // [~NB+8]
    int*   colidx = blksum + 256;               // [E]

    float* out = (float*)d_out;

    const int NB = (N + 1023) / 1024;

    // ---- CSR build (per call; graph-capture safe, no state carried) ----
    hipMemsetAsync(cnt, 0, (size_t)N * sizeof(int), stream);
    hist_kernel <<<(E + 255) / 256, 256, 0, stream>>>(dst, cnt, E);
    scan1_kernel<<<NB, 256, 0, stream>>>(cnt, rowptr, blksum, N);
    scan2_kernel<<<1, 64, 0, stream>>>(blksum, NB);
    scan3_kernel<<<NB, 256, 0, stream>>>(rowptr, blksum, N);
    invdeg_kernel<<<(N + 255) / 256, 256, 0, stream>>>(rowptr, invd, N);
    hipMemsetAsync(cnt, 0, (size_t)N * sizeof(int), stream);
    fill_kernel <<<(E + 255) / 256, 256, 0, stream>>>(src, dst, rowptr, cnt, colidx, E);

    const int ggrid = (N + 3) / 4;
    dim3 g128(128, 2), g64(128, 1);

    // layer 0
    gather_kernel<<<ggrid, 256, 0, stream>>>(x, rowptr, colidx, invd, A, N);
    sage_gemm<128, true><<<g128, 256, 0, stream>>>(A, x, Wl0, Wr0, b0, H0, N);

    // layer 1
    gather_kernel<<<ggrid, 256, 0, stream>>>(H0, rowptr, colidx, invd, A, N);
    sage_gemm<128, true><<<g128, 256, 0, stream>>>(A, H0, Wl1, Wr1, b1, H1, N);

    // layer 2 (d_out = 64, no relu)
    gather_kernel<<<ggrid, 256, 0, stream>>>(H1, rowptr, colidx, invd, A, N);
    sage_gemm<64, false><<<g64, 256, 0, stream>>>(A, H1, Wl2, Wr2, b2, out, N);
}

// Round 9
// 558.968 us; speedup vs baseline: 15.6922x; 1.9566x over previous
//
#include <hip/hip_runtime.h>

#define D 128
typedef unsigned short u16;
typedef unsigned int u32;
typedef __attribute__((ext_vector_type(8))) short short8;
typedef __attribute__((ext_vector_type(16))) float float16;

__device__ __forceinline__ u16 f2bf(float f) {
    u32 u = __builtin_bit_cast(u32, f);
    u += 0x7FFFu + ((u >> 16) & 1u);   // round-to-nearest-even
    return (u16)(u >> 16);
}
__device__ __forceinline__ float bf2f(u16 b) {
    return __builtin_bit_cast(float, ((u32)b) << 16);
}
__device__ __forceinline__ short8 zero8() {
    short8 z;
    #pragma unroll
    for (int i = 0; i < 8; ++i) z[i] = 0;
    return z;
}

// ---------------- CSR build ----------------

__global__ __launch_bounds__(256) void hist_kernel(const int* __restrict__ dst,
                                                   int* __restrict__ cnt, int E) {
    int e = blockIdx.x * 256 + threadIdx.x;
    if (e < E) atomicAdd(&cnt[dst[e]], 1);
}

__global__ __launch_bounds__(256) void scan1_kernel(const int* __restrict__ cnt,
        int* __restrict__ rowptr, int* __restrict__ blksum, int N) {
    __shared__ int sdata[256];
    const int base = blockIdx.x * 1024 + threadIdx.x * 4;
    int v0 = 0, v1 = 0, v2 = 0, v3 = 0;
    if (base + 3 < N) {
        int4 q = *reinterpret_cast<const int4*>(cnt + base);
        v0 = q.x; v1 = q.y; v2 = q.z; v3 = q.w;
    } else {
        if (base + 0 < N) v0 = cnt[base + 0];
        if (base + 1 < N) v1 = cnt[base + 1];
        if (base + 2 < N) v2 = cnt[base + 2];
    }
    const int t = v0 + v1 + v2 + v3;
    int val = t;
    sdata[threadIdx.x] = val;
    __syncthreads();
    for (int off = 1; off < 256; off <<= 1) {
        int other = (threadIdx.x >= off) ? sdata[threadIdx.x - off] : 0;
        __syncthreads();
        val += other;
        sdata[threadIdx.x] = val;
        __syncthreads();
    }
    const int excl = val - t;
    if (base + 0 < N) rowptr[base + 0] = excl;
    if (base + 1 < N) rowptr[base + 1] = excl + v0;
    if (base + 2 < N) rowptr[base + 2] = excl + v0 + v1;
    if (base + 3 < N) rowptr[base + 3] = excl + v0 + v1 + v2;
    if (threadIdx.x == 255) blksum[blockIdx.x] = val;
}

// parallel scan over <=256 block sums, single block
__global__ __launch_bounds__(256) void scan2_kernel(int* __restrict__ blksum, int nb) {
    __shared__ int s[256];
    const int t = threadIdx.x;
    const int v = (t < nb) ? blksum[t] : 0;
    int val = v;
    s[t] = val;
    __syncthreads();
    for (int off = 1; off < 256; off <<= 1) {
        int o = (t >= off) ? s[t - off] : 0;
        __syncthreads();
        val += o;
        s[t] = val;
        __syncthreads();
    }
    if (t < nb) blksum[t] = val - v;   // exclusive
    if (t == 255) blksum[nb] = val;    // grand total
}

__global__ __launch_bounds__(256) void scan3_kernel(int* __restrict__ rowptr,
        const int* __restrict__ blksum, int N) {
    const int base = blockIdx.x * 1024 + threadIdx.x * 4;
    const int off = blksum[blockIdx.x];
    #pragma unroll
    for (int k = 0; k < 4; ++k)
        if (base + k < N) rowptr[base + k] += off;
    if (base == 0 && blockIdx.x == 0) rowptr[N] = blksum[gridDim.x];
}

__global__ __launch_bounds__(256) void invdeg_kernel(const int* __restrict__ rowptr,
        float* __restrict__ invd, int N) {
    int i = blockIdx.x * 256 + threadIdx.x;
    if (i < N) {
        int deg = rowptr[i + 1] - rowptr[i];
        invd[i] = 1.0f / (float)(deg > 1 ? deg : 1);
    }
}

__global__ __launch_bounds__(256) void fill_kernel(const int* __restrict__ src,
        const int* __restrict__ dst, const int* __restrict__ rowptr,
        int* __restrict__ fillc, int* __restrict__ colidx, int E) {
    int e = blockIdx.x * 256 + threadIdx.x;
    if (e < E) {
        int d = dst[e];
        int pos = rowptr[d] + atomicAdd(&fillc[d], 1);
        colidx[pos] = src[e];
    }
}

// ---------------- fp32 -> bf16 convert (x input) ----------------
__global__ __launch_bounds__(256) void tobf16_kernel(const float* __restrict__ in,
        u16* __restrict__ outb, int n8) {
    int i = blockIdx.x * 256 + threadIdx.x;
    if (i >= n8) return;
    float4 a = *reinterpret_cast<const float4*>(in + (size_t)i * 8);
    float4 b = *reinterpret_cast<const float4*>(in + (size_t)i * 8 + 4);
    short8 r;
    r[0] = (short)f2bf(a.x); r[1] = (short)f2bf(a.y);
    r[2] = (short)f2bf(a.z); r[3] = (short)f2bf(a.w);
    r[4] = (short)f2bf(b.x); r[5] = (short)f2bf(b.y);
    r[6] = (short)f2bf(b.z); r[7] = (short)f2bf(b.w);
    *reinterpret_cast<short8*>(outb + (size_t)i * 8) = r;
}

// ---------------- gather mean (bf16 in, bf16 out, fp32 accum) ----------------
// one wave per node; lane covers 2 bf16 cols => 256B coalesced read per edge
__global__ __launch_bounds__(256) void gather_kernel(const u16* __restrict__ xin,
        const int* __restrict__ rowptr, const int* __restrict__ colidx,
        const float* __restrict__ invd, u16* __restrict__ outA, int N) {
    const int node = blockIdx.x * 4 + (threadIdx.x >> 6);
    if (node >= N) return;
    const int lane = threadIdx.x & 63;
    const int beg = rowptr[node], end = rowptr[node + 1];
    float ax = 0.f, ay = 0.f;
    int j = beg;
    for (; j + 4 <= end; j += 4) {
        int s0 = colidx[j + 0], s1 = colidx[j + 1];
        int s2 = colidx[j + 2], s3 = colidx[j + 3];
        u32 v0 = *reinterpret_cast<const u32*>(xin + (size_t)s0 * D + lane * 2);
        u32 v1 = *reinterpret_cast<const u32*>(xin + (size_t)s1 * D + lane * 2);
        u32 v2 = *reinterpret_cast<const u32*>(xin + (size_t)s2 * D + lane * 2);
        u32 v3 = *reinterpret_cast<const u32*>(xin + (size_t)s3 * D + lane * 2);
        ax += bf2f((u16)v0) + bf2f((u16)v1) + bf2f((u16)v2) + bf2f((u16)v3);
        ay += bf2f((u16)(v0 >> 16)) + bf2f((u16)(v1 >> 16)) +
              bf2f((u16)(v2 >> 16)) + bf2f((u16)(v3 >> 16));
    }
    for (; j < end; ++j) {
        int s = colidx[j];
        u32 v = *reinterpret_cast<const u32*>(xin + (size_t)s * D + lane * 2);
        ax += bf2f((u16)v);
        ay += bf2f((u16)(v >> 16));
    }
    const float ic = invd[node];
    u32 o = (u32)f2bf(ax * ic) | ((u32)f2bf(ay * ic) << 16);
    *reinterpret_cast<u32*>(outA + (size_t)node * D + lane * 2) = o;
}

// ---------------- MFMA GEMM: out = [mean|x] @ [Wl|Wr]^T + b ----------------
// Block: 256 thr (4 waves), tile 256 rows x DOUT cols, K=256, BK=64 dbuf LDS.
// mfma_f32_32x32x16_bf16; A-frag: row=lane&31, k=(lane>>5)*8+j (8 contig bf16)
// B-frag: col=lane&31, same k; C/D: col=lane&31, row=(e&3)+8*(e>>2)+4*(lane>>5).
template<int DOUT, bool RELU, bool BF16OUT>
__global__ __launch_bounds__(256) void sage_gemm(
    const u16* __restrict__ Abf, const u16* __restrict__ Xbf,
    const float* __restrict__ Wl, const float* __restrict__ Wr,
    const float* __restrict__ bias, float* __restrict__ outf,
    u16* __restrict__ outb, int N, int nchunks)
{
    constexpr int BM = 256;
    constexpr int NKB = 4;                    // K=256 in 4 slices of 64
    constexpr int WR = (DOUT == 128) ? 2 : 4; // wave grid rows
    constexpr int WC = 4 / WR;
    constexpr int WTM = BM / WR;              // rows per wave: 128 or 64
    constexpr int WTN = DOUT / WC;            // cols per wave: 64
    constexpr int MR = WTM / 32;
    constexpr int NC = WTN / 32;
    constexpr int LDA = 72;                   // 64 + 8 bf16 pad (16B)
    constexpr int LDW = 264;                  // 256 + 8 pad

    __shared__ u16 sW[DOUT][LDW];
    __shared__ u16 sA[2][BM][LDA];

    const int tid = threadIdx.x;
    const int lane = tid & 63;
    const int w = tid >> 6;
    const int wr = w % WR;
    const int wc = w / WR;

    // weights fp32 -> bf16 LDS, concatenated [c][0:128]=Wl[c], [128:256]=Wr[c].
    // 256 bf16 per row = 64 float4 conversions per row (FIX: was DOUT*32 with
    // a q<16 split -> only half the row written, Wr region uninitialized -> NaN).
    for (int i = tid; i < DOUT * 64; i += 256) {
        const int c = i >> 6, q = i & 63;
        const float* sp = (q < 32) ? (Wl + (size_t)c * 128 + q * 4)
                                   : (Wr + (size_t)c * 128 + (q - 32) * 4);
        float4 wv = *reinterpret_cast<const float4*>(sp);
        u32* dp = reinterpret_cast<u32*>(&sW[c][q * 4]);
        dp[0] = (u32)f2bf(wv.x) | ((u32)f2bf(wv.y) << 16);
        dp[1] = (u32)f2bf(wv.z) | ((u32)f2bf(wv.w) << 16);
    }

    short8 rg[2][4];

    auto STAGE = [&](int kb, int m0) {
        const u16* srcb = (kb < 2) ? Abf : Xbf;
        const int koff = (kb & 1) * 64;
        #pragma unroll
        for (int p = 0; p < 2; ++p) {
            const int r = (tid >> 1) + p * 128;
            const int row = m0 + r;
            const u16* sp = srcb + (size_t)row * D + koff + (tid & 1) * 32;
            if (row < N) {
                #pragma unroll
                for (int uu = 0; uu < 4; ++uu)
                    rg[p][uu] = *reinterpret_cast<const short8*>(sp + uu * 8);
            } else {
                #pragma unroll
                for (int uu = 0; uu < 4; ++uu) rg[p][uu] = zero8();
            }
        }
    };
    auto WLDS = [&](int buf) {
        #pragma unroll
        for (int p = 0; p < 2; ++p) {
            const int r = (tid >> 1) + p * 128;
            u16* dp = &sA[buf][r][(tid & 1) * 32];
            #pragma unroll
            for (int uu = 0; uu < 4; ++uu)
                *reinterpret_cast<short8*>(dp + uu * 8) = rg[p][uu];
        }
    };

    for (int chunk = blockIdx.x; chunk < nchunks; chunk += gridDim.x) {
        const int m0 = chunk * BM;
        STAGE(0, m0);
        __syncthreads();          // prior chunk readers done; weight writes visible
        WLDS(0);

        float16 acc[MR][NC];
        #pragma unroll
        for (int mi = 0; mi < MR; ++mi)
            #pragma unroll
            for (int ni = 0; ni < NC; ++ni)
                #pragma unroll
                for (int e = 0; e < 16; ++e) acc[mi][ni][e] = 0.f;

        #pragma unroll
        for (int kb = 0; kb < NKB; ++kb) {
            if (kb + 1 < NKB) STAGE(kb + 1, m0);   // issue loads early
            __syncthreads();                        // buf[kb&1] ready
            #pragma unroll
            for (int ks = 0; ks < 4; ++ks) {
                short8 af[MR], bfv[NC];
                #pragma unroll
                for (int mi = 0; mi < MR; ++mi)
                    af[mi] = *reinterpret_cast<const short8*>(
                        &sA[kb & 1][wr * WTM + mi * 32 + (lane & 31)]
                           [ks * 16 + (lane >> 5) * 8]);
                #pragma unroll
                for (int ni = 0; ni < NC; ++ni)
                    bfv[ni] = *reinterpret_cast<const short8*>(
                        &sW[wc * WTN + ni * 32 + (lane & 31)]
                           [kb * 64 + ks * 16 + (lane >> 5) * 8]);
                #pragma unroll
                for (int mi = 0; mi < MR; ++mi)
                    #pragma unroll
                    for (int ni = 0; ni < NC; ++ni)
                        acc[mi][ni] = __builtin_amdgcn_mfma_f32_32x32x16_bf16(
                            af[mi], bfv[ni], acc[mi][ni], 0, 0, 0);
            }
            if (kb + 1 < NKB) WLDS((kb + 1) & 1);  // write other buffer, no barrier
        }

        #pragma unroll
        for (int ni = 0; ni < NC; ++ni) {
            const int col = wc * WTN + ni * 32 + (lane & 31);
            const float bv = bias[col];
            #pragma unroll
            for (int mi = 0; mi < MR; ++mi) {
                #pragma unroll
                for (int e = 0; e < 16; ++e) {
                    const int row = wr * WTM + mi * 32 + 4 * (lane >> 5)
                                    + (e & 3) + 8 * (e >> 2);
                    const int grow = m0 + row;
                    if (grow < N) {
                        float v = acc[mi][ni][e] + bv;
                        if (RELU) v = fmaxf(v, 0.f);
                        if (BF16OUT) outb[(size_t)grow * DOUT + col] = f2bf(v);
                        else         outf[(size_t)grow * DOUT + col] = v;
                    }
                }
            }
        }
    }
}

extern "C" void kernel_launch(void* const* d_in, const int* in_sizes, int n_in,
                              void* d_out, int out_size, void* d_ws, size_t ws_size,
                              hipStream_t stream) {
    const float* x   = (const float*)d_in[0];
    const float* Wl0 = (const float*)d_in[1];
    const float* Wr0 = (const float*)d_in[2];
    const float* b0  = (const float*)d_in[3];
    const float* Wl1 = (const float*)d_in[4];
    const float* Wr1 = (const float*)d_in[5];
    const float* b1  = (const float*)d_in[6];
    const float* Wl2 = (const float*)d_in[7];
    const float* Wr2 = (const float*)d_in[8];
    const float* b2  = (const float*)d_in[9];
    const int* ei    = (const int*)d_in[10];

    const int E = in_sizes[10] / 2;
    const int N = in_sizes[0] / D;
    const int* src = ei;
    const int* dst = ei + E;

    // workspace
    u16* Xbf = (u16*)d_ws;                      // [N][128]
    u16* Abf = Xbf + (size_t)N * D;             // [N][128] mean
    u16* H0  = Abf + (size_t)N * D;             // [N][128]
    u16* H1  = H0 + (size_t)N * D;              // [N][128]
    float* invd   = (float*)(H1 + (size_t)N * D);
    int*   cnt    = (int*)(invd + N);
    int*   rowptr = cnt + N;                    // [N+8]
    int*   blksum = rowptr + N + 8;             // [512]
    int*   colidx = blksum + 512;               // [E]
    float* out = (float*)d_out;

    const int NB = (N + 1023) / 1024;

    hipMemsetAsync(cnt, 0, (size_t)N * sizeof(int), stream);
    hist_kernel <<<(E + 255) / 256, 256, 0, stream>>>(dst, cnt, E);
    scan1_kernel<<<NB, 256, 0, stream>>>(cnt, rowptr, blksum, N);
    scan2_kernel<<<1, 256, 0, stream>>>(blksum, NB);
    scan3_kernel<<<NB, 256, 0, stream>>>(rowptr, blksum, N);
    invdeg_kernel<<<(N + 255) / 256, 256, 0, stream>>>(rowptr, invd, N);
    hipMemsetAsync(cnt, 0, (size_t)N * sizeof(int), stream);
    fill_kernel <<<(E + 255) / 256, 256, 0, stream>>>(src, dst, rowptr, cnt, colidx, E);

    tobf16_kernel<<<(N * D / 8 + 255) / 256, 256, 0, stream>>>(x, Xbf, N * D / 8);

    const int ggrid = (N + 3) / 4;
    const int nchunks = (N + 255) / 256;
    const int ggemm = (nchunks + 1) / 2;   // 2 chunks per block, weights loaded once

    // layer 0
    gather_kernel<<<ggrid, 256, 0, stream>>>(Xbf, rowptr, colidx, invd, Abf, N);
    sage_gemm<128, true, true><<<ggemm, 256, 0, stream>>>(
        Abf, Xbf, Wl0, Wr0, b0, nullptr, H0, N, nchunks);

    // layer 1
    gather_kernel<<<ggrid, 256, 0, stream>>>(H0, rowptr, colidx, invd, Abf, N);
    sage_gemm<128, true, true><<<ggemm, 256, 0, stream>>>(
        Abf, H0, Wl1, Wr1, b1, nullptr, H1, N, nchunks);

    // layer 2
    gather_kernel<<<ggrid, 256, 0, stream>>>(H1, rowptr, colidx, invd, Abf, N);
    sage_gemm<64, false, false><<<ggemm, 256, 0, stream>>>(
        Abf, H1, Wl2, Wr2, b2, out, nullptr, N, nchunks);
}

// Round 11
// 540.686 us; speedup vs baseline: 16.2228x; 1.0338x over previous
//
#include <hip/hip_runtime.h>

#define D 128
typedef unsigned short u16;
typedef unsigned int u32;
typedef __attribute__((ext_vector_type(8))) short short8;
typedef __attribute__((ext_vector_type(16))) float float16;

__device__ __forceinline__ u16 f2bf(float f) {
    u32 u = __builtin_bit_cast(u32, f);
    u += 0x7FFFu + ((u >> 16) & 1u);   // round-to-nearest-even
    return (u16)(u >> 16);
}
__device__ __forceinline__ float bf2f(u16 b) {
    return __builtin_bit_cast(float, ((u32)b) << 16);
}
__device__ __forceinline__ short8 zero8() {
    short8 z;
    #pragma unroll
    for (int i = 0; i < 8; ++i) z[i] = 0;
    return z;
}

// ---------------- CSR build ----------------

__global__ __launch_bounds__(256) void hist_kernel(const int* __restrict__ dst,
                                                   int* __restrict__ cnt, int E) {
    int e = blockIdx.x * 256 + threadIdx.x;
    if (e < E) atomicAdd(&cnt[dst[e]], 1);
}

__global__ __launch_bounds__(256) void scan1_kernel(const int* __restrict__ cnt,
        int* __restrict__ rowptr, int* __restrict__ blksum, int N) {
    __shared__ int sdata[256];
    const int base = blockIdx.x * 1024 + threadIdx.x * 4;
    int v0 = 0, v1 = 0, v2 = 0, v3 = 0;
    if (base + 3 < N) {
        int4 q = *reinterpret_cast<const int4*>(cnt + base);
        v0 = q.x; v1 = q.y; v2 = q.z; v3 = q.w;
    } else {
        if (base + 0 < N) v0 = cnt[base + 0];
        if (base + 1 < N) v1 = cnt[base + 1];
        if (base + 2 < N) v2 = cnt[base + 2];
    }
    const int t = v0 + v1 + v2 + v3;
    int val = t;
    sdata[threadIdx.x] = val;
    __syncthreads();
    for (int off = 1; off < 256; off <<= 1) {
        int other = (threadIdx.x >= off) ? sdata[threadIdx.x - off] : 0;
        __syncthreads();
        val += other;
        sdata[threadIdx.x] = val;
        __syncthreads();
    }
    const int excl = val - t;
    if (base + 0 < N) rowptr[base + 0] = excl;
    if (base + 1 < N) rowptr[base + 1] = excl + v0;
    if (base + 2 < N) rowptr[base + 2] = excl + v0 + v1;
    if (base + 3 < N) rowptr[base + 3] = excl + v0 + v1 + v2;
    if (threadIdx.x == 255) blksum[blockIdx.x] = val;
}

// parallel scan over <=256 block sums, single block
__global__ __launch_bounds__(256) void scan2_kernel(int* __restrict__ blksum, int nb) {
    __shared__ int s[256];
    const int t = threadIdx.x;
    const int v = (t < nb) ? blksum[t] : 0;
    int val = v;
    s[t] = val;
    __syncthreads();
    for (int off = 1; off < 256; off <<= 1) {
        int o = (t >= off) ? s[t - off] : 0;
        __syncthreads();
        val += o;
        s[t] = val;
        __syncthreads();
    }
    if (t < nb) blksum[t] = val - v;   // exclusive
    if (t == 255) blksum[nb] = val;    // grand total
}

__global__ __launch_bounds__(256) void scan3_kernel(int* __restrict__ rowptr,
        const int* __restrict__ blksum, int N) {
    const int base = blockIdx.x * 1024 + threadIdx.x * 4;
    const int off = blksum[blockIdx.x];
    #pragma unroll
    for (int k = 0; k < 4; ++k)
        if (base + k < N) rowptr[base + k] += off;
    if (base == 0 && blockIdx.x == 0) rowptr[N] = blksum[gridDim.x];
}

__global__ __launch_bounds__(256) void invdeg_kernel(const int* __restrict__ rowptr,
        float* __restrict__ invd, int N) {
    int i = blockIdx.x * 256 + threadIdx.x;
    if (i < N) {
        int deg = rowptr[i + 1] - rowptr[i];
        invd[i] = 1.0f / (float)(deg > 1 ? deg : 1);
    }
}

__global__ __launch_bounds__(256) void fill_kernel(const int* __restrict__ src,
        const int* __restrict__ dst, const int* __restrict__ rowptr,
        int* __restrict__ fillc, int* __restrict__ colidx, int E) {
    int e = blockIdx.x * 256 + threadIdx.x;
    if (e < E) {
        int d = dst[e];
        int pos = rowptr[d] + atomicAdd(&fillc[d], 1);
        colidx[pos] = src[e];
    }
}

// ---------------- fp32 -> bf16 convert (x input) ----------------
__global__ __launch_bounds__(256) void tobf16_kernel(const float* __restrict__ in,
        u16* __restrict__ outb, int n8) {
    int i = blockIdx.x * 256 + threadIdx.x;
    if (i >= n8) return;
    float4 a = *reinterpret_cast<const float4*>(in + (size_t)i * 8);
    float4 b = *reinterpret_cast<const float4*>(in + (size_t)i * 8 + 4);
    short8 r;
    r[0] = (short)f2bf(a.x); r[1] = (short)f2bf(a.y);
    r[2] = (short)f2bf(a.z); r[3] = (short)f2bf(a.w);
    r[4] = (short)f2bf(b.x); r[5] = (short)f2bf(b.y);
    r[6] = (short)f2bf(b.z); r[7] = (short)f2bf(b.w);
    *reinterpret_cast<short8*>(outb + (size_t)i * 8) = r;
}

// ---------------- gather mean (bf16 in, bf16 out, fp32 accum) ----------------
// One wave per node. 16 lanes cover a 256B row (dwordx4/lane); groups g=lane>>4
// process 4 edges concurrently, 2-deep unrolled (8 edges / iter, 2 loads in
// flight). One global_load_dwordx4 serves 4 edges (1KB/instr) vs 1 edge with
// the old 64x4B layout -> 4x fewer VMEM instructions on a latency-bound loop.
__global__ __launch_bounds__(256) void gather_kernel(const u16* __restrict__ xin,
        const int* __restrict__ rowptr, const int* __restrict__ colidx,
        const float* __restrict__ invd, u16* __restrict__ outA, int N) {
    const int node = blockIdx.x * 4 + (threadIdx.x >> 6);
    if (node >= N) return;
    const int lane = threadIdx.x & 63;
    const int g = lane >> 4;          // edge subgroup 0..3
    const int r = lane & 15;          // col group: bf16 cols [r*8, r*8+8)
    const int beg = rowptr[node];
    const int nb = rowptr[node + 1] - beg;   // degree (wave-uniform)

    float a0 = 0.f, a1 = 0.f, a2 = 0.f, a3 = 0.f;
    float a4 = 0.f, a5 = 0.f, a6 = 0.f, a7 = 0.f;

    for (int base = 0; base < nb; base += 8) {
        const bool p0 = (base + g) < nb;
        const bool p1 = (base + 4 + g) < nb;
        uint4 v0 = make_uint4(0, 0, 0, 0), v1 = v0;
        if (p0) {
            int s0 = colidx[beg + base + g];
            v0 = *reinterpret_cast<const uint4*>(xin + (size_t)s0 * D + r * 8);
        }
        if (p1) {
            int s1 = colidx[beg + base + 4 + g];
            v1 = *reinterpret_cast<const uint4*>(xin + (size_t)s1 * D + r * 8);
        }
        a0 += bf2f((u16)v0.x) + bf2f((u16)v1.x);
        a1 += bf2f((u16)(v0.x >> 16)) + bf2f((u16)(v1.x >> 16));
        a2 += bf2f((u16)v0.y) + bf2f((u16)v1.y);
        a3 += bf2f((u16)(v0.y >> 16)) + bf2f((u16)(v1.y >> 16));
        a4 += bf2f((u16)v0.z) + bf2f((u16)v1.z);
        a5 += bf2f((u16)(v0.z >> 16)) + bf2f((u16)(v1.z >> 16));
        a6 += bf2f((u16)v0.w) + bf2f((u16)v1.w);
        a7 += bf2f((u16)(v0.w >> 16)) + bf2f((u16)(v1.w >> 16));
    }

    // combine the 4 edge-subgroups: butterfly over lane bits 4,5
    #pragma unroll
    for (int m = 16; m <= 32; m <<= 1) {
        a0 += __shfl_xor(a0, m, 64); a1 += __shfl_xor(a1, m, 64);
        a2 += __shfl_xor(a2, m, 64); a3 += __shfl_xor(a3, m, 64);
        a4 += __shfl_xor(a4, m, 64); a5 += __shfl_xor(a5, m, 64);
        a6 += __shfl_xor(a6, m, 64); a7 += __shfl_xor(a7, m, 64);
    }

    if (g == 0) {
        const float ic = invd[node];
        uint4 o;
        o.x = (u32)f2bf(a0 * ic) | ((u32)f2bf(a1 * ic) << 16);
        o.y = (u32)f2bf(a2 * ic) | ((u32)f2bf(a3 * ic) << 16);
        o.z = (u32)f2bf(a4 * ic) | ((u32)f2bf(a5 * ic) << 16);
        o.w = (u32)f2bf(a6 * ic) | ((u32)f2bf(a7 * ic) << 16);
        *reinterpret_cast<uint4*>(outA + (size_t)node * D + r * 8) = o;
    }
}

// ---------------- MFMA GEMM: out = [mean|x] @ [Wl|Wr]^T + b ----------------
// Block: 256 thr (4 waves), tile 256 rows x DOUT cols, K=256, BK=64 dbuf LDS.
// mfma_f32_32x32x16_bf16; A-frag: row=lane&31, k=(lane>>5)*8+j (8 contig bf16)
// B-frag: col=lane&31, same k; C/D: col=lane&31, row=(e&3)+8*(e>>2)+4*(lane>>5).
template<int DOUT, bool RELU, bool BF16OUT>
__global__ __launch_bounds__(256) void sage_gemm(
    const u16* __restrict__ Abf, const u16* __restrict__ Xbf,
    const float* __restrict__ Wl, const float* __restrict__ Wr,
    const float* __restrict__ bias, float* __restrict__ outf,
    u16* __restrict__ outb, int N, int nchunks)
{
    constexpr int BM = 256;
    constexpr int NKB = 4;                    // K=256 in 4 slices of 64
    constexpr int WR = (DOUT == 128) ? 2 : 4; // wave grid rows
    constexpr int WC = 4 / WR;
    constexpr int WTM = BM / WR;              // rows per wave: 128 or 64
    constexpr int WTN = DOUT / WC;            // cols per wave: 64
    constexpr int MR = WTM / 32;
    constexpr int NC = WTN / 32;
    constexpr int LDA = 72;                   // 64 + 8 bf16 pad (16B)
    constexpr int LDW = 264;                  // 256 + 8 pad

    __shared__ u16 sW[DOUT][LDW];
    __shared__ u16 sA[2][BM][LDA];

    const int tid = threadIdx.x;
    const int lane = tid & 63;
    const int w = tid >> 6;
    const int wr = w % WR;
    const int wc = w / WR;

    // weights fp32 -> bf16 LDS, concatenated [c][0:128]=Wl[c], [128:256]=Wr[c].
    // 256 bf16 per row = 64 float4 conversions per row.
    for (int i = tid; i < DOUT * 64; i += 256) {
        const int c = i >> 6, q = i & 63;
        const float* sp = (q < 32) ? (Wl + (size_t)c * 128 + q * 4)
                                   : (Wr + (size_t)c * 128 + (q - 32) * 4);
        float4 wv = *reinterpret_cast<const float4*>(sp);
        u32* dp = reinterpret_cast<u32*>(&sW[c][q * 4]);
        dp[0] = (u32)f2bf(wv.x) | ((u32)f2bf(wv.y) << 16);
        dp[1] = (u32)f2bf(wv.z) | ((u32)f2bf(wv.w) << 16);
    }

    short8 rg[2][4];

    auto STAGE = [&](int kb, int m0) {
        const u16* srcb = (kb < 2) ? Abf : Xbf;
        const int koff = (kb & 1) * 64;
        #pragma unroll
        for (int p = 0; p < 2; ++p) {
            const int r = (tid >> 1) + p * 128;
            const int row = m0 + r;
            const u16* sp = srcb + (size_t)row * D + koff + (tid & 1) * 32;
            if (row < N) {
                #pragma unroll
                for (int uu = 0; uu < 4; ++uu)
                    rg[p][uu] = *reinterpret_cast<const short8*>(sp + uu * 8);
            } else {
                #pragma unroll
                for (int uu = 0; uu < 4; ++uu) rg[p][uu] = zero8();
            }
        }
    };
    auto WLDS = [&](int buf) {
        #pragma unroll
        for (int p = 0; p < 2; ++p) {
            const int r = (tid >> 1) + p * 128;
            u16* dp = &sA[buf][r][(tid & 1) * 32];
            #pragma unroll
            for (int uu = 0; uu < 4; ++uu)
                *reinterpret_cast<short8*>(dp + uu * 8) = rg[p][uu];
        }
    };

    for (int chunk = blockIdx.x; chunk < nchunks; chunk += gridDim.x) {
        const int m0 = chunk * BM;
        STAGE(0, m0);
        __syncthreads();          // prior chunk readers done; weight writes visible
        WLDS(0);

        float16 acc[MR][NC];
        #pragma unroll
        for (int mi = 0; mi < MR; ++mi)
            #pragma unroll
            for (int ni = 0; ni < NC; ++ni)
                #pragma unroll
                for (int e = 0; e < 16; ++e) acc[mi][ni][e] = 0.f;

        #pragma unroll
        for (int kb = 0; kb < NKB; ++kb) {
            if (kb + 1 < NKB) STAGE(kb + 1, m0);   // issue loads early
            __syncthreads();                        // buf[kb&1] ready
            #pragma unroll
            for (int ks = 0; ks < 4; ++ks) {
                short8 af[MR], bfv[NC];
                #pragma unroll
                for (int mi = 0; mi < MR; ++mi)
                    af[mi] = *reinterpret_cast<const short8*>(
                        &sA[kb & 1][wr * WTM + mi * 32 + (lane & 31)]
                           [ks * 16 + (lane >> 5) * 8]);
                #pragma unroll
                for (int ni = 0; ni < NC; ++ni)
                    bfv[ni] = *reinterpret_cast<const short8*>(
                        &sW[wc * WTN + ni * 32 + (lane & 31)]
                           [kb * 64 + ks * 16 + (lane >> 5) * 8]);
                #pragma unroll
                for (int mi = 0; mi < MR; ++mi)
                    #pragma unroll
                    for (int ni = 0; ni < NC; ++ni)
                        acc[mi][ni] = __builtin_amdgcn_mfma_f32_32x32x16_bf16(
                            af[mi], bfv[ni], acc[mi][ni], 0, 0, 0);
            }
            if (kb + 1 < NKB) WLDS((kb + 1) & 1);  // write other buffer, no barrier
        }

        #pragma unroll
        for (int ni = 0; ni < NC; ++ni) {
            const int col = wc * WTN + ni * 32 + (lane & 31);
            const float bv = bias[col];
            #pragma unroll
            for (int mi = 0; mi < MR; ++mi) {
                #pragma unroll
                for (int e = 0; e < 16; ++e) {
                    const int row = wr * WTM + mi * 32 + 4 * (lane >> 5)
                                    + (e & 3) + 8 * (e >> 2);
                    const int grow = m0 + row;
                    if (grow < N) {
                        float v = acc[mi][ni][e] + bv;
                        if (RELU) v = fmaxf(v, 0.f);
                        if (BF16OUT) outb[(size_t)grow * DOUT + col] = f2bf(v);
                        else         outf[(size_t)grow * DOUT + col] = v;
                    }
                }
            }
        }
    }
}

extern "C" void kernel_launch(void* const* d_in, const int* in_sizes, int n_in,
                              void* d_out, int out_size, void* d_ws, size_t ws_size,
                              hipStream_t stream) {
    const float* x   = (const float*)d_in[0];
    const float* Wl0 = (const float*)d_in[1];
    const float* Wr0 = (const float*)d_in[2];
    const float* b0  = (const float*)d_in[3];
    const float* Wl1 = (const float*)d_in[4];
    const float* Wr1 = (const float*)d_in[5];
    const float* b1  = (const float*)d_in[6];
    const float* Wl2 = (const float*)d_in[7];
    const float* Wr2 = (const float*)d_in[8];
    const float* b2  = (const float*)d_in[9];
    const int* ei    = (const int*)d_in[10];

    const int E = in_sizes[10] / 2;
    const int N = in_sizes[0] / D;
    const int* src = ei;
    const int* dst = ei + E;

    // workspace
    u16* Xbf = (u16*)d_ws;                      // [N][128]
    u16* Abf = Xbf + (size_t)N * D;             // [N][128] mean
    u16* H0  = Abf + (size_t)N * D;             // [N][128]
    u16* H1  = H0 + (size_t)N * D;              // [N][128]
    float* invd   = (float*)(H1 + (size_t)N * D);
    int*   cnt    = (int*)(invd + N);
    int*   rowptr = cnt + N;                    // [N+8]
    int*   blksum = rowptr + N + 8;             // [512]
    int*   colidx = blksum + 512;               // [E]
    float* out = (float*)d_out;

    const int NB = (N + 1023) / 1024;

    hipMemsetAsync(cnt, 0, (size_t)N * sizeof(int), stream);
    hist_kernel <<<(E + 255) / 256, 256, 0, stream>>>(dst, cnt, E);
    scan1_kernel<<<NB, 256, 0, stream>>>(cnt, rowptr, blksum, N);
    scan2_kernel<<<1, 256, 0, stream>>>(blksum, NB);
    scan3_kernel<<<NB, 256, 0, stream>>>(rowptr, blksum, N);
    invdeg_kernel<<<(N + 255) / 256, 256, 0, stream>>>(rowptr, invd, N);
    hipMemsetAsync(cnt, 0, (size_t)N * sizeof(int), stream);
    fill_kernel <<<(E + 255) / 256, 256, 0, stream>>>(src, dst, rowptr, cnt, colidx, E);

    tobf16_kernel<<<(N * D / 8 + 255) / 256, 256, 0, stream>>>(x, Xbf, N * D / 8);

    const int ggrid = (N + 3) / 4;
    const int nchunks = (N + 255) / 256;
    const int ggemm = (nchunks + 1) / 2;   // 2 chunks per block, weights loaded once

    // layer 0
    gather_kernel<<<ggrid, 256, 0, stream>>>(Xbf, rowptr, colidx, invd, Abf, N);
    sage_gemm<128, true, true><<<ggemm, 256, 0, stream>>>(
        Abf, Xbf, Wl0, Wr0, b0, nullptr, H0, N, nchunks);

    // layer 1
    gather_kernel<<<ggrid, 256, 0, stream>>>(H0, rowptr, colidx, invd, Abf, N);
    sage_gemm<128, true, true><<<ggemm, 256, 0, stream>>>(
        Abf, H0, Wl1, Wr1, b1, nullptr, H1, N, nchunks);

    // layer 2
    gather_kernel<<<ggrid, 256, 0, stream>>>(H1, rowptr, colidx, invd, Abf, N);
    sage_gemm<64, false, false><<<ggemm, 256, 0, stream>>>(
        Abf, H1, Wl2, Wr2, b2, out, nullptr, N, nchunks);
}

// Round 13
// 518.712 us; speedup vs baseline: 16.9101x; 1.0424x over previous
//
#include <hip/hip_runtime.h>

#define D 128
typedef unsigned short u16;
typedef unsigned int u32;
typedef __attribute__((ext_vector_type(8))) short short8;
typedef __attribute__((ext_vector_type(16))) float float16;

__device__ __forceinline__ u16 f2bf(float f) {
    u32 u = __builtin_bit_cast(u32, f);
    u += 0x7FFFu + ((u >> 16) & 1u);   // round-to-nearest-even
    return (u16)(u >> 16);
}
__device__ __forceinline__ float bf2f(u16 b) {
    return __builtin_bit_cast(float, ((u32)b) << 16);
}
__device__ __forceinline__ short8 zero8() {
    short8 z;
    #pragma unroll
    for (int i = 0; i < 8; ++i) z[i] = 0;
    return z;
}

// ---------------- CSR build ----------------

// histogram + per-edge rank (atomic return value). rank write is coalesced.
__global__ __launch_bounds__(256) void hist_kernel(const int* __restrict__ dst,
        int* __restrict__ cnt, int* __restrict__ rank, int E) {
    int e = blockIdx.x * 256 + threadIdx.x;
    if (e < E) rank[e] = atomicAdd(&cnt[dst[e]], 1);
}

__global__ __launch_bounds__(256) void scan1_kernel(const int* __restrict__ cnt,
        int* __restrict__ rowptr, int* __restrict__ blksum, int N) {
    __shared__ int sdata[256];
    const int base = blockIdx.x * 1024 + threadIdx.x * 4;
    int v0 = 0, v1 = 0, v2 = 0, v3 = 0;
    if (base + 3 < N) {
        int4 q = *reinterpret_cast<const int4*>(cnt + base);
        v0 = q.x; v1 = q.y; v2 = q.z; v3 = q.w;
    } else {
        if (base + 0 < N) v0 = cnt[base + 0];
        if (base + 1 < N) v1 = cnt[base + 1];
        if (base + 2 < N) v2 = cnt[base + 2];
    }
    const int t = v0 + v1 + v2 + v3;
    int val = t;
    sdata[threadIdx.x] = val;
    __syncthreads();
    for (int off = 1; off < 256; off <<= 1) {
        int other = (threadIdx.x >= off) ? sdata[threadIdx.x - off] : 0;
        __syncthreads();
        val += other;
        sdata[threadIdx.x] = val;
        __syncthreads();
    }
    const int excl = val - t;
    if (base + 0 < N) rowptr[base + 0] = excl;
    if (base + 1 < N) rowptr[base + 1] = excl + v0;
    if (base + 2 < N) rowptr[base + 2] = excl + v0 + v1;
    if (base + 3 < N) rowptr[base + 3] = excl + v0 + v1 + v2;
    if (threadIdx.x == 255) blksum[blockIdx.x] = val;
}

// parallel scan over <=256 block sums, single block
__global__ __launch_bounds__(256) void scan2_kernel(int* __restrict__ blksum, int nb) {
    __shared__ int s[256];
    const int t = threadIdx.x;
    const int v = (t < nb) ? blksum[t] : 0;
    int val = v;
    s[t] = val;
    __syncthreads();
    for (int off = 1; off < 256; off <<= 1) {
        int o = (t >= off) ? s[t - off] : 0;
        __syncthreads();
        val += o;
        s[t] = val;
        __syncthreads();
    }
    if (t < nb) blksum[t] = val - v;   // exclusive
    if (t == 255) blksum[nb] = val;    // grand total
}

__global__ __launch_bounds__(256) void scan3_kernel(int* __restrict__ rowptr,
        const int* __restrict__ blksum, int N) {
    const int base = blockIdx.x * 1024 + threadIdx.x * 4;
    const int off = blksum[blockIdx.x];
    #pragma unroll
    for (int k = 0; k < 4; ++k)
        if (base + k < N) rowptr[base + k] += off;
    if (base == 0 && blockIdx.x == 0) rowptr[N] = blksum[gridDim.x];
}

__global__ __launch_bounds__(256) void invdeg_kernel(const int* __restrict__ rowptr,
        float* __restrict__ invd, int N) {
    int i = blockIdx.x * 256 + threadIdx.x;
    if (i < N) {
        int deg = rowptr[i + 1] - rowptr[i];
        invd[i] = 1.0f / (float)(deg > 1 ? deg : 1);
    }
}

// atomic-free fill: position = rowptr[dst] + precomputed rank
__global__ __launch_bounds__(256) void fill_kernel(const int* __restrict__ src,
        const int* __restrict__ dst, const int* __restrict__ rowptr,
        const int* __restrict__ rank, int* __restrict__ colidx, int E) {
    int e = blockIdx.x * 256 + threadIdx.x;
    if (e < E) {
        int d = dst[e];
        colidx[rowptr[d] + rank[e]] = src[e];
    }
}

// ---------------- fp32 -> bf16 convert (x input) ----------------
__global__ __launch_bounds__(256) void tobf16_kernel(const float* __restrict__ in,
        u16* __restrict__ outb, int n8) {
    int i = blockIdx.x * 256 + threadIdx.x;
    if (i >= n8) return;
    float4 a = *reinterpret_cast<const float4*>(in + (size_t)i * 8);
    float4 b = *reinterpret_cast<const float4*>(in + (size_t)i * 8 + 4);
    short8 r;
    r[0] = (short)f2bf(a.x); r[1] = (short)f2bf(a.y);
    r[2] = (short)f2bf(a.z); r[3] = (short)f2bf(a.w);
    r[4] = (short)f2bf(b.x); r[5] = (short)f2bf(b.y);
    r[6] = (short)f2bf(b.z); r[7] = (short)f2bf(b.w);
    *reinterpret_cast<short8*>(outb + (size_t)i * 8) = r;
}

// ---------------- gather mean, 128-wide rows (bf16) ----------------
__global__ __launch_bounds__(256) void gather_kernel(const u16* __restrict__ xin,
        const int* __restrict__ rowptr, const int* __restrict__ colidx,
        const float* __restrict__ invd, u16* __restrict__ outA, int N) {
    const int node = blockIdx.x * 4 + (threadIdx.x >> 6);
    if (node >= N) return;
    const int lane = threadIdx.x & 63;
    const int g = lane >> 4;          // edge subgroup 0..3
    const int r = lane & 15;          // col group: bf16 cols [r*8, r*8+8)
    const int beg = rowptr[node];
    const int nb = rowptr[node + 1] - beg;

    float a0 = 0.f, a1 = 0.f, a2 = 0.f, a3 = 0.f;
    float a4 = 0.f, a5 = 0.f, a6 = 0.f, a7 = 0.f;

    for (int base = 0; base < nb; base += 8) {
        const bool p0 = (base + g) < nb;
        const bool p1 = (base + 4 + g) < nb;
        uint4 v0 = make_uint4(0, 0, 0, 0), v1 = v0;
        if (p0) {
            int s0 = colidx[beg + base + g];
            v0 = *reinterpret_cast<const uint4*>(xin + (size_t)s0 * D + r * 8);
        }
        if (p1) {
            int s1 = colidx[beg + base + 4 + g];
            v1 = *reinterpret_cast<const uint4*>(xin + (size_t)s1 * D + r * 8);
        }
        a0 += bf2f((u16)v0.x) + bf2f((u16)v1.x);
        a1 += bf2f((u16)(v0.x >> 16)) + bf2f((u16)(v1.x >> 16));
        a2 += bf2f((u16)v0.y) + bf2f((u16)v1.y);
        a3 += bf2f((u16)(v0.y >> 16)) + bf2f((u16)(v1.y >> 16));
        a4 += bf2f((u16)v0.z) + bf2f((u16)v1.z);
        a5 += bf2f((u16)(v0.z >> 16)) + bf2f((u16)(v1.z >> 16));
        a6 += bf2f((u16)v0.w) + bf2f((u16)v1.w);
        a7 += bf2f((u16)(v0.w >> 16)) + bf2f((u16)(v1.w >> 16));
    }

    #pragma unroll
    for (int m = 16; m <= 32; m <<= 1) {
        a0 += __shfl_xor(a0, m, 64); a1 += __shfl_xor(a1, m, 64);
        a2 += __shfl_xor(a2, m, 64); a3 += __shfl_xor(a3, m, 64);
        a4 += __shfl_xor(a4, m, 64); a5 += __shfl_xor(a5, m, 64);
        a6 += __shfl_xor(a6, m, 64); a7 += __shfl_xor(a7, m, 64);
    }

    if (g == 0) {
        const float ic = invd[node];
        uint4 o;
        o.x = (u32)f2bf(a0 * ic) | ((u32)f2bf(a1 * ic) << 16);
        o.y = (u32)f2bf(a2 * ic) | ((u32)f2bf(a3 * ic) << 16);
        o.z = (u32)f2bf(a4 * ic) | ((u32)f2bf(a5 * ic) << 16);
        o.w = (u32)f2bf(a6 * ic) | ((u32)f2bf(a7 * ic) << 16);
        *reinterpret_cast<uint4*>(outA + (size_t)node * D + r * 8) = o;
    }
}

// ---------------- gather mean, 64-wide rows (bf16) — layer-2 path ----------------
// 128B rows: 16 lanes x uint2 (4 bf16); 4 edge subgroups, 2-deep unroll.
__global__ __launch_bounds__(256) void gather64_kernel(const u16* __restrict__ yin,
        const int* __restrict__ rowptr, const int* __restrict__ colidx,
        const float* __restrict__ invd, u16* __restrict__ outM, int N) {
    const int node = blockIdx.x * 4 + (threadIdx.x >> 6);
    if (node >= N) return;
    const int lane = threadIdx.x & 63;
    const int g = lane >> 4;
    const int r = lane & 15;          // bf16 cols [r*4, r*4+4)
    const int beg = rowptr[node];
    const int nb = rowptr[node + 1] - beg;

    float a0 = 0.f, a1 = 0.f, a2 = 0.f, a3 = 0.f;

    for (int base = 0; base < nb; base += 8) {
        const bool p0 = (base + g) < nb;
        const bool p1 = (base + 4 + g) < nb;
        uint2 v0 = make_uint2(0, 0), v1 = v0;
        if (p0) {
            int s0 = colidx[beg + base + g];
            v0 = *reinterpret_cast<const uint2*>(yin + (size_t)s0 * 64 + r * 4);
        }
        if (p1) {
            int s1 = colidx[beg + base + 4 + g];
            v1 = *reinterpret_cast<const uint2*>(yin + (size_t)s1 * 64 + r * 4);
        }
        a0 += bf2f((u16)v0.x) + bf2f((u16)v1.x);
        a1 += bf2f((u16)(v0.x >> 16)) + bf2f((u16)(v1.x >> 16));
        a2 += bf2f((u16)v0.y) + bf2f((u16)v1.y);
        a3 += bf2f((u16)(v0.y >> 16)) + bf2f((u16)(v1.y >> 16));
    }

    #pragma unroll
    for (int m = 16; m <= 32; m <<= 1) {
        a0 += __shfl_xor(a0, m, 64); a1 += __shfl_xor(a1, m, 64);
        a2 += __shfl_xor(a2, m, 64); a3 += __shfl_xor(a3, m, 64);
    }

    if (g == 0) {
        const float ic = invd[node];
        uint2 o;
        o.x = (u32)f2bf(a0 * ic) | ((u32)f2bf(a1 * ic) << 16);
        o.y = (u32)f2bf(a2 * ic) | ((u32)f2bf(a3 * ic) << 16);
        *reinterpret_cast<uint2*>(outM + (size_t)node * 64 + r * 4) = o;
    }
}

// ---------------- dual MFMA GEMM: out = [mean|x] @ [Wl|Wr]^T + b (layers 0,1) --------
template<int DOUT, bool RELU, bool BF16OUT>
__global__ __launch_bounds__(256) void sage_gemm(
    const u16* __restrict__ Abf, const u16* __restrict__ Xbf,
    const float* __restrict__ Wl, const float* __restrict__ Wr,
    const float* __restrict__ bias, float* __restrict__ outf,
    u16* __restrict__ outb, int N, int nchunks)
{
    constexpr int BM = 256;
    constexpr int NKB = 4;
    constexpr int WR = (DOUT == 128) ? 2 : 4;
    constexpr int WC = 4 / WR;
    constexpr int WTM = BM / WR;
    constexpr int WTN = DOUT / WC;
    constexpr int MR = WTM / 32;
    constexpr int NC = WTN / 32;
    constexpr int LDA = 72;
    constexpr int LDW = 264;

    __shared__ u16 sW[DOUT][LDW];
    __shared__ u16 sA[2][BM][LDA];

    const int tid = threadIdx.x;
    const int lane = tid & 63;
    const int w = tid >> 6;
    const int wr = w % WR;
    const int wc = w / WR;

    for (int i = tid; i < DOUT * 64; i += 256) {
        const int c = i >> 6, q = i & 63;
        const float* sp = (q < 32) ? (Wl + (size_t)c * 128 + q * 4)
                                   : (Wr + (size_t)c * 128 + (q - 32) * 4);
        float4 wv = *reinterpret_cast<const float4*>(sp);
        u32* dp = reinterpret_cast<u32*>(&sW[c][q * 4]);
        dp[0] = (u32)f2bf(wv.x) | ((u32)f2bf(wv.y) << 16);
        dp[1] = (u32)f2bf(wv.z) | ((u32)f2bf(wv.w) << 16);
    }

    short8 rg[2][4];

    auto STAGE = [&](int kb, int m0) {
        const u16* srcb = (kb < 2) ? Abf : Xbf;
        const int koff = (kb & 1) * 64;
        #pragma unroll
        for (int p = 0; p < 2; ++p) {
            const int r = (tid >> 1) + p * 128;
            const int row = m0 + r;
            const u16* sp = srcb + (size_t)row * D + koff + (tid & 1) * 32;
            if (row < N) {
                #pragma unroll
                for (int uu = 0; uu < 4; ++uu)
                    rg[p][uu] = *reinterpret_cast<const short8*>(sp + uu * 8);
            } else {
                #pragma unroll
                for (int uu = 0; uu < 4; ++uu) rg[p][uu] = zero8();
            }
        }
    };
    auto WLDS = [&](int buf) {
        #pragma unroll
        for (int p = 0; p < 2; ++p) {
            const int r = (tid >> 1) + p * 128;
            u16* dp = &sA[buf][r][(tid & 1) * 32];
            #pragma unroll
            for (int uu = 0; uu < 4; ++uu)
                *reinterpret_cast<short8*>(dp + uu * 8) = rg[p][uu];
        }
    };

    for (int chunk = blockIdx.x; chunk < nchunks; chunk += gridDim.x) {
        const int m0 = chunk * BM;
        STAGE(0, m0);
        __syncthreads();
        WLDS(0);

        float16 acc[MR][NC];
        #pragma unroll
        for (int mi = 0; mi < MR; ++mi)
            #pragma unroll
            for (int ni = 0; ni < NC; ++ni)
                #pragma unroll
                for (int e = 0; e < 16; ++e) acc[mi][ni][e] = 0.f;

        #pragma unroll
        for (int kb = 0; kb < NKB; ++kb) {
            if (kb + 1 < NKB) STAGE(kb + 1, m0);
            __syncthreads();
            #pragma unroll
            for (int ks = 0; ks < 4; ++ks) {
                short8 af[MR], bfv[NC];
                #pragma unroll
                for (int mi = 0; mi < MR; ++mi)
                    af[mi] = *reinterpret_cast<const short8*>(
                        &sA[kb & 1][wr * WTM + mi * 32 + (lane & 31)]
                           [ks * 16 + (lane >> 5) * 8]);
                #pragma unroll
                for (int ni = 0; ni < NC; ++ni)
                    bfv[ni] = *reinterpret_cast<const short8*>(
                        &sW[wc * WTN + ni * 32 + (lane & 31)]
                           [kb * 64 + ks * 16 + (lane >> 5) * 8]);
                #pragma unroll
                for (int mi = 0; mi < MR; ++mi)
                    #pragma unroll
                    for (int ni = 0; ni < NC; ++ni)
                        acc[mi][ni] = __builtin_amdgcn_mfma_f32_32x32x16_bf16(
                            af[mi], bfv[ni], acc[mi][ni], 0, 0, 0);
            }
            if (kb + 1 < NKB) WLDS((kb + 1) & 1);
        }

        #pragma unroll
        for (int ni = 0; ni < NC; ++ni) {
            const int col = wc * WTN + ni * 32 + (lane & 31);
            const float bv = bias[col];
            #pragma unroll
            for (int mi = 0; mi < MR; ++mi) {
                #pragma unroll
                for (int e = 0; e < 16; ++e) {
                    const int row = wr * WTM + mi * 32 + 4 * (lane >> 5)
                                    + (e & 3) + 8 * (e >> 2);
                    const int grow = m0 + row;
                    if (grow < N) {
                        float v = acc[mi][ni][e] + bv;
                        if (RELU) v = fmaxf(v, 0.f);
                        if (BF16OUT) outb[(size_t)grow * DOUT + col] = f2bf(v);
                        else         outf[(size_t)grow * DOUT + col] = v;
                    }
                }
            }
        }
    }
}

// ---------------- single-operand GEMM (DOUT=64, K=128) for layer 2 ----------------
// out = In @ W^T  [+ mean2 + bias]. ADDMEAN: add bf16 mean2[N][64]. BF16OUT: bf16 out.
template<bool ADDMEAN, bool BF16OUT, bool BIAS>
__global__ __launch_bounds__(256) void lin_gemm(
    const u16* __restrict__ In, const float* __restrict__ W,
    const float* __restrict__ bias, const u16* __restrict__ mean2,
    float* __restrict__ outf, u16* __restrict__ outb, int N, int nchunks)
{
    constexpr int DOUT = 64;
    constexpr int BM = 256;
    constexpr int NKB = 2;      // K=128 in 2 slices of 64
    constexpr int WTM = 64;     // 4 waves stacked on rows
    constexpr int MR = 2, NC = 2;
    constexpr int LDA = 72;
    constexpr int LDW = 136;    // 128 + 8 pad

    __shared__ u16 sW[DOUT][LDW];
    __shared__ u16 sA[2][BM][LDA];

    const int tid = threadIdx.x;
    const int lane = tid & 63;
    const int wr = tid >> 6;

    // stage W (64x128 f32) as bf16
    for (int i = tid; i < DOUT * 32; i += 256) {
        const int c = i >> 5, q = i & 31;
        float4 wv = *reinterpret_cast<const float4*>(W + (size_t)c * 128 + q * 4);
        u32* dp = reinterpret_cast<u32*>(&sW[c][q * 4]);
        dp[0] = (u32)f2bf(wv.x) | ((u32)f2bf(wv.y) << 16);
        dp[1] = (u32)f2bf(wv.z) | ((u32)f2bf(wv.w) << 16);
    }

    short8 rg[2][4];

    auto STAGE = [&](int kb, int m0) {
        const int koff = kb * 64;
        #pragma unroll
        for (int p = 0; p < 2; ++p) {
            const int r = (tid >> 1) + p * 128;
            const int row = m0 + r;
            const u16* sp = In + (size_t)row * D + koff + (tid & 1) * 32;
            if (row < N) {
                #pragma unroll
                for (int uu = 0; uu < 4; ++uu)
                    rg[p][uu] = *reinterpret_cast<const short8*>(sp + uu * 8);
            } else {
                #pragma unroll
                for (int uu = 0; uu < 4; ++uu) rg[p][uu] = zero8();
            }
        }
    };
    auto WLDS = [&](int buf) {
        #pragma unroll
        for (int p = 0; p < 2; ++p) {
            const int r = (tid >> 1) + p * 128;
            u16* dp = &sA[buf][r][(tid & 1) * 32];
            #pragma unroll
            for (int uu = 0; uu < 4; ++uu)
                *reinterpret_cast<short8*>(dp + uu * 8) = rg[p][uu];
        }
    };

    for (int chunk = blockIdx.x; chunk < nchunks; chunk += gridDim.x) {
        const int m0 = chunk * BM;
        STAGE(0, m0);
        __syncthreads();
        WLDS(0);

        float16 acc[MR][NC];
        #pragma unroll
        for (int mi = 0; mi < MR; ++mi)
            #pragma unroll
            for (int ni = 0; ni < NC; ++ni)
                #pragma unroll
                for (int e = 0; e < 16; ++e) acc[mi][ni][e] = 0.f;

        #pragma unroll
        for (int kb = 0; kb < NKB; ++kb) {
            if (kb + 1 < NKB) STAGE(kb + 1, m0);
            __syncthreads();
            #pragma unroll
            for (int ks = 0; ks < 4; ++ks) {
                short8 af[MR], bfv[NC];
                #pragma unroll
                for (int mi = 0; mi < MR; ++mi)
                    af[mi] = *reinterpret_cast<const short8*>(
                        &sA[kb & 1][wr * WTM + mi * 32 + (lane & 31)]
                           [ks * 16 + (lane >> 5) * 8]);
                #pragma unroll
                for (int ni = 0; ni < NC; ++ni)
                    bfv[ni] = *reinterpret_cast<const short8*>(
                        &sW[ni * 32 + (lane & 31)]
                           [kb * 64 + ks * 16 + (lane >> 5) * 8]);
                #pragma unroll
                for (int mi = 0; mi < MR; ++mi)
                    #pragma unroll
                    for (int ni = 0; ni < NC; ++ni)
                        acc[mi][ni] = __builtin_amdgcn_mfma_f32_32x32x16_bf16(
                            af[mi], bfv[ni], acc[mi][ni], 0, 0, 0);
            }
            if (kb + 1 < NKB) WLDS((kb + 1) & 1);
        }

        #pragma unroll
        for (int ni = 0; ni < NC; ++ni) {
            const int col = ni * 32 + (lane & 31);
            const float bv = BIAS ? bias[col] : 0.f;
            #pragma unroll
            for (int mi = 0; mi < MR; ++mi) {
                #pragma unroll
                for (int e = 0; e < 16; ++e) {
                    const int row = wr * WTM + mi * 32 + 4 * (lane >> 5)
                                    + (e & 3) + 8 * (e >> 2);
                    const int grow = m0 + row;
                    if (grow < N) {
                        float v = acc[mi][ni][e] + bv;
                        if (ADDMEAN) v += bf2f(mean2[(size_t)grow * 64 + col]);
                        if (BF16OUT) outb[(size_t)grow * DOUT + col] = f2bf(v);
                        else         outf[(size_t)grow * DOUT + col] = v;
                    }
                }
            }
        }
    }
}

extern "C" void kernel_launch(void* const* d_in, const int* in_sizes, int n_in,
                              void* d_out, int out_size, void* d_ws, size_t ws_size,
                              hipStream_t stream) {
    const float* x   = (const float*)d_in[0];
    const float* Wl0 = (const float*)d_in[1];
    const float* Wr0 = (const float*)d_in[2];
    const float* b0  = (const float*)d_in[3];
    const float* Wl1 = (const float*)d_in[4];
    const float* Wr1 = (const float*)d_in[5];
    const float* b1  = (const float*)d_in[6];
    const float* Wl2 = (const float*)d_in[7];
    const float* Wr2 = (const float*)d_in[8];
    const float* b2  = (const float*)d_in[9];
    const int* ei    = (const int*)d_in[10];

    const int E = in_sizes[10] / 2;
    const int N = in_sizes[0] / D;
    const int* src = ei;
    const int* dst = ei + E;

    // workspace
    u16* Xbf = (u16*)d_ws;                      // [N][128]
    u16* Abf = Xbf + (size_t)N * D;             // [N][128] mean (L0/L1); L2: y2|mean2
    u16* H0  = Abf + (size_t)N * D;             // [N][128]
    u16* H1  = H0 + (size_t)N * D;              // [N][128]
    float* invd   = (float*)(H1 + (size_t)N * D);
    int*   cnt    = (int*)(invd + N);
    int*   rowptr = cnt + N;                    // [N+8]
    int*   blksum = rowptr + N + 8;             // [512]
    int*   colidx = blksum + 512;               // [E]
    int*   rank   = colidx + E;                 // [E]
    float* out = (float*)d_out;

    u16* y2    = Abf;                           // [N][64] (L2 transform)
    u16* mean2 = Abf + (size_t)N * 64;          // [N][64]

    const int NB = (N + 1023) / 1024;

    hipMemsetAsync(cnt, 0, (size_t)N * sizeof(int), stream);
    hist_kernel <<<(E + 255) / 256, 256, 0, stream>>>(dst, cnt, rank, E);
    scan1_kernel<<<NB, 256, 0, stream>>>(cnt, rowptr, blksum, N);
    scan2_kernel<<<1, 256, 0, stream>>>(blksum, NB);
    scan3_kernel<<<NB, 256, 0, stream>>>(rowptr, blksum, N);
    invdeg_kernel<<<(N + 255) / 256, 256, 0, stream>>>(rowptr, invd, N);
    fill_kernel <<<(E + 255) / 256, 256, 0, stream>>>(src, dst, rowptr, rank, colidx, E);

    tobf16_kernel<<<(N * D / 8 + 255) / 256, 256, 0, stream>>>(x, Xbf, N * D / 8);

    const int ggrid = (N + 3) / 4;
    const int nchunks = (N + 255) / 256;
    const int ggemm = (nchunks + 1) / 2;

    // layer 0
    gather_kernel<<<ggrid, 256, 0, stream>>>(Xbf, rowptr, colidx, invd, Abf, N);
    sage_gemm<128, true, true><<<ggemm, 256, 0, stream>>>(
        Abf, Xbf, Wl0, Wr0, b0, nullptr, H0, N, nchunks);

    // layer 1
    gather_kernel<<<ggrid, 256, 0, stream>>>(H0, rowptr, colidx, invd, Abf, N);
    sage_gemm<128, true, true><<<ggemm, 256, 0, stream>>>(
        Abf, H0, Wl1, Wr1, b1, nullptr, H1, N, nchunks);

    // layer 2: transform-before-aggregate (aggregation is linear; 64-wide gather)
    lin_gemm<false, true, false><<<ggemm, 256, 0, stream>>>(
        H1, Wl2, nullptr, nullptr, nullptr, y2, N, nchunks);
    gather64_kernel<<<ggrid, 256, 0, stream>>>(y2, rowptr, colidx, invd, mean2, N);
    lin_gemm<true, false, true><<<ggemm, 256, 0, stream>>>(
        H1, Wr2, b2, mean2, out, nullptr, N, nchunks);
}